// Round 1
// baseline (447.245 us; speedup 1.0000x reference)
//
#include <hip/hip_runtime.h>

#define BB 128
#define TT 1496
#define CC 768

// Kernel 1: p[b,t] = dot(hidden_states[b,t,:], W)  for t < audio_lengths[b]
// One wave (64 lanes) per (b,t) row. Row = 768 floats = 192 float4;
// lane i reads float4 at {i, i+64, i+128} (fully coalesced 16B/lane).
__global__ __launch_bounds__(256) void row_dot_kernel(
    const float* __restrict__ h,      // (B,T,C)
    const float* __restrict__ W,      // (C)
    const int* __restrict__ lens,     // (B)
    float* __restrict__ p)            // (B,T) workspace
{
    const int lane = threadIdx.x & 63;
    const int wv   = threadIdx.x >> 6;            // 0..3
    const int t    = blockIdx.x * 4 + wv;
    const int b    = blockIdx.y;
    if (t >= TT) return;
    if (t >= lens[b]) return;                      // skip invalid frames entirely

    const float4* row = reinterpret_cast<const float4*>(h + ((size_t)b * TT + t) * CC);
    const float4* w4  = reinterpret_cast<const float4*>(W);

    float4 a0 = row[lane];
    float4 a1 = row[lane + 64];
    float4 a2 = row[lane + 128];
    float4 w0 = w4[lane];
    float4 w1 = w4[lane + 64];
    float4 w2 = w4[lane + 128];

    float s = a0.x * w0.x + a0.y * w0.y + a0.z * w0.z + a0.w * w0.w
            + a1.x * w1.x + a1.y * w1.y + a1.z * w1.z + a1.w * w1.w
            + a2.x * w2.x + a2.y * w2.y + a2.z * w2.z + a2.w * w2.w;

    // wave64 butterfly reduce
    #pragma unroll
    for (int off = 32; off > 0; off >>= 1)
        s += __shfl_down(s, off, 64);

    if (lane == 0)
        p[b * TT + t] = s;
}

// Kernel 2: per batch row, serial run-length scan over p + phoneme_ids.
// logit[b] = (1/n_runs) * sum_runs( mean_t_in_run p[b,t] ) + bias
__global__ void finalize_kernel(
    const float* __restrict__ p,      // (B,T)
    const int* __restrict__ ids,      // (B,T)
    const int* __restrict__ lens,     // (B)
    const float* __restrict__ bias,   // (1)
    float* __restrict__ out)          // (B,1) -> B floats
{
    int row = blockIdx.x * blockDim.x + threadIdx.x;
    if (row >= BB) return;

    int L = lens[row];
    if (L < 1) L = 1;
    if (L > TT) L = TT;

    const float* pr = p + row * TT;
    const int*   ir = ids + row * TT;

    float acc = 0.0f;
    int   nr  = 0;
    int   cur = ir[0];
    float rs  = pr[0];
    float rl  = 1.0f;

    for (int t = 1; t < L; ++t) {
        int   id = ir[t];
        float v  = pr[t];
        if (id != cur) {
            acc += rs / rl;
            nr  += 1;
            cur = id;
            rs  = v;
            rl  = 1.0f;
        } else {
            rs += v;
            rl += 1.0f;
        }
    }
    acc += rs / rl;
    nr  += 1;

    out[row] = acc / (float)nr + bias[0];
}

extern "C" void kernel_launch(void* const* d_in, const int* in_sizes, int n_in,
                              void* d_out, int out_size, void* d_ws, size_t ws_size,
                              hipStream_t stream) {
    const float* h    = (const float*)d_in[0];   // (B,T,C) fp32
    const float* W    = (const float*)d_in[1];   // (1,C)   fp32
    const float* bias = (const float*)d_in[2];   // (1,)    fp32
    const int*   ids  = (const int*)d_in[3];     // (B,T)   int32
    const int*   lens = (const int*)d_in[4];     // (B,)    int32

    float* out = (float*)d_out;                  // (B,1) fp32
    float* p   = (float*)d_ws;                   // (B,T) fp32 scratch

    dim3 grid1((TT + 3) / 4, BB);
    row_dot_kernel<<<grid1, 256, 0, stream>>>(h, W, lens, p);

    finalize_kernel<<<(BB + 127) / 128, 128, 0, stream>>>(p, ids, lens, bias, out);
}

// Round 3
// 88.353 us; speedup vs baseline: 5.0620x; 5.0620x over previous
//
#include <hip/hip_runtime.h>

#define BB 128
#define TT 1496
#define CC 768

// Kernel 1: p[b,t] = dot(hidden_states[b,t,:], W) for t < audio_lengths[b],
//           p[b,t] = 0 otherwise (so every workspace cell is rewritten
//           deterministically on every call - no poison can leak through).
// One wave (64 lanes) per (b,t) row. Row = 768 floats = 192 float4;
// lane i reads float4 at {i, i+64, i+128} (fully coalesced 16B/lane).
__global__ __launch_bounds__(256) void row_dot_kernel(
    const float* __restrict__ h,      // (B,T,C)
    const float* __restrict__ W,      // (C)
    const int* __restrict__ lens,     // (B)
    float* __restrict__ p)            // (B,T) workspace
{
    const int lane = threadIdx.x & 63;
    const int wv   = threadIdx.x >> 6;            // 0..3
    const int t    = blockIdx.x * 4 + wv;
    const int b    = blockIdx.y;
    if (t >= TT) return;

    if (t >= lens[b]) {                            // invalid frame: write 0, skip h read
        if (lane == 0) p[b * TT + t] = 0.0f;
        return;
    }

    const float4* row = reinterpret_cast<const float4*>(h + ((size_t)b * TT + t) * CC);
    const float4* w4  = reinterpret_cast<const float4*>(W);

    float4 a0 = row[lane];
    float4 a1 = row[lane + 64];
    float4 a2 = row[lane + 128];
    float4 w0 = w4[lane];
    float4 w1 = w4[lane + 64];
    float4 w2 = w4[lane + 128];

    float s = a0.x * w0.x + a0.y * w0.y + a0.z * w0.z + a0.w * w0.w
            + a1.x * w1.x + a1.y * w1.y + a1.z * w1.z + a1.w * w1.w
            + a2.x * w2.x + a2.y * w2.y + a2.z * w2.z + a2.w * w2.w;

    // wave64 tree reduce into lane 0
    #pragma unroll
    for (int off = 32; off > 0; off >>= 1)
        s += __shfl_down(s, off, 64);

    if (lane == 0)
        p[b * TT + t] = s;
}

// Kernel 2: one block (256 threads) per batch row. Each thread owns the runs
// that START at its frames (t==0 or id change vs t-1); ids uniform over 100
// bins so runs avg ~1.01 long. Reads straight from global (p and ids are
// ~765 KB each - fully L2-resident); LDS used only for the final 8-scalar
// cross-wave reduction.
__global__ __launch_bounds__(256) void finalize_kernel(
    const float* __restrict__ p,      // (B,T)
    const int* __restrict__ ids,      // (B,T)
    const int* __restrict__ lens,     // (B)
    const float* __restrict__ bias,   // (1)
    float* __restrict__ out)          // (B,1) -> B floats
{
    __shared__ float s_acc[4];
    __shared__ float s_cnt[4];

    const int b   = blockIdx.x;
    const int tid = threadIdx.x;

    int L = lens[b];
    if (L < 1) L = 1;
    if (L > TT) L = TT;

    const float* pr = p + b * TT;
    const int*   ir = ids + b * TT;

    float acc = 0.0f;   // sum of run means
    float cnt = 0.0f;   // number of runs

    for (int t = tid; t < L; t += 256) {
        int  id    = ir[t];
        bool start = (t == 0) || (ir[t - 1] != id);
        if (start) {
            float rs = pr[t];
            float rl = 1.0f;
            int   j  = t + 1;
            while (j < L && ir[j] == id) {
                rs += pr[j];
                rl += 1.0f;
                ++j;
            }
            acc += rs / rl;
            cnt += 1.0f;
        }
    }

    // wave64 tree reduce into lane 0 of each wave
    #pragma unroll
    for (int off = 32; off > 0; off >>= 1) {
        acc += __shfl_down(acc, off, 64);
        cnt += __shfl_down(cnt, off, 64);
    }

    const int lane = tid & 63;
    const int wv   = tid >> 6;
    if (lane == 0) { s_acc[wv] = acc; s_cnt[wv] = cnt; }
    __syncthreads();

    if (tid == 0) {
        float a = s_acc[0] + s_acc[1] + s_acc[2] + s_acc[3];
        float c = s_cnt[0] + s_cnt[1] + s_cnt[2] + s_cnt[3];
        out[b] = a / c + bias[0];
    }
}

extern "C" void kernel_launch(void* const* d_in, const int* in_sizes, int n_in,
                              void* d_out, int out_size, void* d_ws, size_t ws_size,
                              hipStream_t stream) {
    const float* h    = (const float*)d_in[0];   // (B,T,C) fp32
    const float* W    = (const float*)d_in[1];   // (1,C)   fp32
    const float* bias = (const float*)d_in[2];   // (1,)    fp32
    const int*   ids  = (const int*)d_in[3];     // (B,T)   int32
    const int*   lens = (const int*)d_in[4];     // (B,)    int32

    float* out = (float*)d_out;                  // (B,1) fp32
    float* p   = (float*)d_ws;                   // (B,T) fp32 scratch

    dim3 grid1((TT + 3) / 4, BB);
    row_dot_kernel<<<grid1, 256, 0, stream>>>(h, W, lens, p);

    finalize_kernel<<<BB, 256, 0, stream>>>(p, ids, lens, bias, out);
}